// Round 1
// baseline (369.238 us; speedup 1.0000x reference)
//
#include <hip/hip_runtime.h>
#include <stdint.h>

#define M_DIM 16384
#define N_DIM 4096
#define K_DIM 4096

#define BM 256
#define BN 128
#define BK 128

typedef int i32x4 __attribute__((ext_vector_type(4)));

// ---- async global->LDS 16B (dest = wave-uniform base + lane*16) ----
__device__ __forceinline__ void async16(const uint8_t* g, uint8_t* l) {
    __builtin_amdgcn_global_load_lds(
        (const __attribute__((address_space(1))) void*)g,
        (__attribute__((address_space(3))) void*)l,
        16, 0, 0);
}

// ---------------- weight pack: int32 -> int8 ----------------
__global__ __launch_bounds__(256) void pack_w_kernel(const int* __restrict__ w32,
                                                     uint32_t* __restrict__ w8,
                                                     int n4) {
    int i = blockIdx.x * 256 + threadIdx.x;
    if (i < n4) {
        const int4 v = reinterpret_cast<const int4*>(w32)[i];
        uint32_t p = (uint32_t)(v.x & 255) | ((uint32_t)(v.y & 255) << 8) |
                     ((uint32_t)(v.z & 255) << 16) | ((uint32_t)(v.w & 255) << 24);
        w8[i] = p;
    }
}

// ---------------- per-row dynamic activation quant ----------------
__global__ __launch_bounds__(256) void quant_kernel(const float* __restrict__ x,
                                                    uint32_t* __restrict__ xq,
                                                    float* __restrict__ xscale) {
    const int m = blockIdx.x;
    const int t = threadIdx.x;
    const float4* row = reinterpret_cast<const float4*>(x + (size_t)m * K_DIM);
    float4 v[4];
    float amax = 0.0f;
#pragma unroll
    for (int i = 0; i < 4; ++i) {
        v[i] = row[t + i * 256];
        amax = fmaxf(amax, fmaxf(fmaxf(fabsf(v[i].x), fabsf(v[i].y)),
                                 fmaxf(fabsf(v[i].z), fabsf(v[i].w))));
    }
#pragma unroll
    for (int off = 32; off > 0; off >>= 1) amax = fmaxf(amax, __shfl_xor(amax, off));
    __shared__ float smax[4];
    if ((t & 63) == 0) smax[t >> 6] = amax;
    __syncthreads();
    amax = fmaxf(fmaxf(smax[0], smax[1]), fmaxf(smax[2], smax[3]));
    const float scale = amax / 127.0f;
    const float s = fmaxf(scale, 1e-8f);
    if (t == 0) xscale[m] = scale;
    uint32_t* orow = xq + (size_t)m * (K_DIM / 4);
#pragma unroll
    for (int i = 0; i < 4; ++i) {
        int q0 = __float2int_rn(v[i].x / s);
        int q1 = __float2int_rn(v[i].y / s);
        int q2 = __float2int_rn(v[i].z / s);
        int q3 = __float2int_rn(v[i].w / s);
        q0 = max(-127, min(127, q0));
        q1 = max(-127, min(127, q1));
        q2 = max(-127, min(127, q2));
        q3 = max(-127, min(127, q3));
        uint32_t p = (uint32_t)(q0 & 255) | ((uint32_t)(q1 & 255) << 8) |
                     ((uint32_t)(q2 & 255) << 16) | ((uint32_t)(q3 & 255) << 24);
        orow[t + i * 256] = p;
    }
}

// ---------------- int8 GEMM with fused dequant ----------------
// C[m,n] = (sum_k xq[m,k]*w[n,k]) * xscale[m] * wscale[n]
// Block tile 256x128, BK=128. 4 waves, each owns a 128x64 sub-tile (wr,wc in 2x2).
// LDS: linear dest for global_load_lds; global source pre-swizzled with
// unit ^= (row&7); ds_read applies the same XOR (involution) -> 2-way banks.
__global__ __launch_bounds__(256, 2) void gemm_kernel(
    const uint8_t* __restrict__ Aq, const float* __restrict__ ascale,
    const uint8_t* __restrict__ Bq, const float* __restrict__ wscale,
    float* __restrict__ out) {
    __shared__ uint8_t lds[BM * BK + BN * BK];  // 32KB + 16KB = 48KB
    uint8_t* ldsA = lds;
    uint8_t* ldsB = lds + BM * BK;

    const int tid = threadIdx.x;
    const int lane = tid & 63;
    const int w = tid >> 6;
    const int wr = w >> 1;  // 0..1 -> M offset wr*128
    const int wc = w & 1;   // 0..1 -> N offset wc*64
    const int lr = lane & 15;  // row within 16x16 fragment
    const int lg = lane >> 4;  // lane group 0..3 -> k chunk

    const size_t row0 = (size_t)blockIdx.y * BM;
    const size_t col0 = (size_t)blockIdx.x * BN;
    const uint8_t* aBase = Aq + row0 * K_DIM;
    const uint8_t* bBase = Bq + col0 * K_DIM;

    i32x4 acc[8][4];
#pragma unroll
    for (int i = 0; i < 8; ++i)
#pragma unroll
        for (int j = 0; j < 4; ++j) acc[i][j] = (i32x4){0, 0, 0, 0};

    for (int k0 = 0; k0 < K_DIM; k0 += BK) {
        // stage A: 256 rows x 128B = 2048 x 16B units; idx = it*256 + tid
        // physical (m,p) receives global unit (p ^ (m&7)) of row m
#pragma unroll
        for (int it = 0; it < 8; ++it) {
            const int idx = it * 256 + tid;
            const int m = idx >> 3, p = idx & 7;
            const uint8_t* src = aBase + (size_t)m * K_DIM + k0 + ((p ^ (m & 7)) << 4);
            async16(src, ldsA + (it * 256 + w * 64) * 16);
        }
        // stage B: 128 rows x 128B = 1024 x 16B units
#pragma unroll
        for (int it = 0; it < 4; ++it) {
            const int idx = it * 256 + tid;
            const int n = idx >> 3, p = idx & 7;
            const uint8_t* src = bBase + (size_t)n * K_DIM + k0 + ((p ^ (n & 7)) << 4);
            async16(src, ldsB + (it * 256 + w * 64) * 16);
        }
        __syncthreads();  // drains vmcnt before barrier (compiler-inserted)

#pragma unroll
        for (int kk = 0; kk < 2; ++kk) {
            i32x4 af[8], bf[4];
#pragma unroll
            for (int mf = 0; mf < 8; ++mf) {
                const int r = wr * 128 + mf * 16 + lr;
                const int u = kk * 4 + lg;  // logical 16B unit (k chunk)
                af[mf] = *reinterpret_cast<const i32x4*>(
                    ldsA + r * BK + ((u ^ (r & 7)) << 4));
            }
#pragma unroll
            for (int nf = 0; nf < 4; ++nf) {
                const int r = wc * 64 + nf * 16 + lr;
                const int u = kk * 4 + lg;
                bf[nf] = *reinterpret_cast<const i32x4*>(
                    ldsB + r * BK + ((u ^ (r & 7)) << 4));
            }
#pragma unroll
            for (int mf = 0; mf < 8; ++mf)
#pragma unroll
                for (int nf = 0; nf < 4; ++nf)
                    acc[mf][nf] = __builtin_amdgcn_mfma_i32_16x16x64_i8(
                        af[mf], bf[nf], acc[mf][nf], 0, 0, 0);
        }
        __syncthreads();
    }

    // epilogue: C/D layout col = lane&15, row = (lane>>4)*4 + reg
    const float* asp = ascale + row0 + wr * 128;
    const float* wsp = wscale + col0 + wc * 64;
    float wsv[4];
#pragma unroll
    for (int nf = 0; nf < 4; ++nf) wsv[nf] = wsp[nf * 16 + lr];
    float* outBase = out + (row0 + wr * 128) * (size_t)N_DIM + col0 + wc * 64;
#pragma unroll
    for (int mf = 0; mf < 8; ++mf) {
#pragma unroll
        for (int j = 0; j < 4; ++j) {
            const int r = mf * 16 + lg * 4 + j;
            const float av = asp[r];
            float* orow = outBase + (size_t)r * N_DIM;
#pragma unroll
            for (int nf = 0; nf < 4; ++nf) {
                orow[nf * 16 + lr] = (float)acc[mf][nf][j] * av * wsv[nf];
            }
        }
    }
}

extern "C" void kernel_launch(void* const* d_in, const int* in_sizes, int n_in,
                              void* d_out, int out_size, void* d_ws, size_t ws_size,
                              hipStream_t stream) {
    const float* x = (const float*)d_in[0];
    const int* w32 = (const int*)d_in[1];
    const float* wscale = (const float*)d_in[2];
    float* out = (float*)d_out;

    uint8_t* ws = (uint8_t*)d_ws;
    uint32_t* xq = (uint32_t*)ws;                                  // 64 MiB
    float* xscale = (float*)(ws + (size_t)M_DIM * K_DIM);          // 64 KiB
    uint8_t* wq = ws + (size_t)M_DIM * K_DIM + (size_t)M_DIM * 4;  // 16 MiB

    pack_w_kernel<<<dim3((N_DIM * K_DIM / 4 + 255) / 256), 256, 0, stream>>>(
        w32, (uint32_t*)wq, N_DIM * K_DIM / 4);
    quant_kernel<<<dim3(M_DIM), 256, 0, stream>>>(x, xq, xscale);
    gemm_kernel<<<dim3(N_DIM / BN, M_DIM / BM), 256, 0, stream>>>(
        (const uint8_t*)xq, xscale, wq, wscale, out);
}

// Round 2
// 346.526 us; speedup vs baseline: 1.0655x; 1.0655x over previous
//
#include <hip/hip_runtime.h>
#include <stdint.h>

#define M_DIM 16384
#define N_DIM 4096
#define K_DIM 4096

#define BM 256
#define BN 256
#define BK 128
#define NT (K_DIM / BK)  // 32 K-tiles

typedef int i32x4 __attribute__((ext_vector_type(4)));

// ---- async global->LDS 16B (dest = wave-uniform base, HW adds lane*16) ----
__device__ __forceinline__ void async16(const uint8_t* g, uint8_t* l) {
    __builtin_amdgcn_global_load_lds(
        (const __attribute__((address_space(1))) void*)g,
        (__attribute__((address_space(3))) void*)l,
        16, 0, 0);
}

// ---------------- weight pack: int32 -> int8 ----------------
__global__ __launch_bounds__(256) void pack_w_kernel(const int* __restrict__ w32,
                                                     uint32_t* __restrict__ w8,
                                                     int n4) {
    int i = blockIdx.x * 256 + threadIdx.x;
    if (i < n4) {
        const int4 v = reinterpret_cast<const int4*>(w32)[i];
        uint32_t p = (uint32_t)(v.x & 255) | ((uint32_t)(v.y & 255) << 8) |
                     ((uint32_t)(v.z & 255) << 16) | ((uint32_t)(v.w & 255) << 24);
        w8[i] = p;
    }
}

// ---------------- per-row dynamic activation quant ----------------
__global__ __launch_bounds__(256) void quant_kernel(const float* __restrict__ x,
                                                    uint32_t* __restrict__ xq,
                                                    float* __restrict__ xscale) {
    const int m = blockIdx.x;
    const int t = threadIdx.x;
    const float4* row = reinterpret_cast<const float4*>(x + (size_t)m * K_DIM);
    float4 v[4];
    float amax = 0.0f;
#pragma unroll
    for (int i = 0; i < 4; ++i) {
        v[i] = row[t + i * 256];
        amax = fmaxf(amax, fmaxf(fmaxf(fabsf(v[i].x), fabsf(v[i].y)),
                                 fmaxf(fabsf(v[i].z), fabsf(v[i].w))));
    }
#pragma unroll
    for (int off = 32; off > 0; off >>= 1) amax = fmaxf(amax, __shfl_xor(amax, off));
    __shared__ float smax[4];
    if ((t & 63) == 0) smax[t >> 6] = amax;
    __syncthreads();
    amax = fmaxf(fmaxf(smax[0], smax[1]), fmaxf(smax[2], smax[3]));
    const float scale = amax / 127.0f;
    const float s = fmaxf(scale, 1e-8f);
    if (t == 0) xscale[m] = scale;
    uint32_t* orow = xq + (size_t)m * (K_DIM / 4);
#pragma unroll
    for (int i = 0; i < 4; ++i) {
        int q0 = __float2int_rn(v[i].x / s);
        int q1 = __float2int_rn(v[i].y / s);
        int q2 = __float2int_rn(v[i].z / s);
        int q3 = __float2int_rn(v[i].w / s);
        q0 = max(-127, min(127, q0));
        q1 = max(-127, min(127, q1));
        q2 = max(-127, min(127, q2));
        q3 = max(-127, min(127, q3));
        uint32_t p = (uint32_t)(q0 & 255) | ((uint32_t)(q1 & 255) << 8) |
                     ((uint32_t)(q2 & 255) << 16) | ((uint32_t)(q3 & 255) << 24);
        orow[t + i * 256] = p;
    }
}

// ---------------- int8 GEMM, 256x256 8-phase schedule ----------------
// 512 threads = 8 waves (2M x 4N), per-wave output 128x64.
// K-tile BK=128 (128B rows). LDS: 2 x (A 32KB + B 32KB) = 128KB.
// Phases per K-tile: quadrants (mh,nh) = (0,0),(0,1),(1,1),(1,0);
// A frags reused across 2 phases, B(nh0) held in regs P1->P4.
// Half-tile regions (A-half mh: rows {mh*64+q*128+i}; B-half nh: interleaved
// 32-col groups) are each LDS-read in exactly ONE phase -> race-free staging:
//   P1: A1(t+1)  P2: A0(t+2)  P3: B0(t+2)  P4: B1(t+2) +vmcnt(6)
//   P5: A1(t+2)  P6: A0(t+3)  P7: B0(t+3)  P8: B1(t+3) +vmcnt(6)
// Swizzle: physical 16B-unit p of row r holds global unit p^(r&7)
// (pre-swizzled global source, linear LDS dest, XOR on ds_read).
__global__ __launch_bounds__(512, 2) void gemm_kernel(
    const uint8_t* __restrict__ Aq, const float* __restrict__ ascale,
    const uint8_t* __restrict__ Bq, const float* __restrict__ wscale,
    float* __restrict__ out) {
    __shared__ uint8_t lds[2 * BM * BK + 2 * BN * BK];
    uint8_t* ldsA0 = lds;
    uint8_t* ldsA1 = lds + BM * BK;
    uint8_t* ldsB0 = lds + 2 * BM * BK;
    uint8_t* ldsB1 = lds + 2 * BM * BK + BN * BK;

    const int tid = threadIdx.x;
    const int lane = tid & 63;
    const int w = tid >> 6;
    const int wr = w >> 2;    // 0..1 -> M offset wr*128
    const int wc = w & 3;     // 0..3 -> N offset wc*64
    const int lr = lane & 15; // row within 16x16 fragment
    const int lg = lane >> 4; // k-group 0..3 (16B each)
    const int aa = lane >> 3; // staging: row-within-8
    const int pp = lane & 7;  // staging: unit-within-row

    // XCD-aware bijective swizzle (1024 blocks, 1024%8==0)
    const int bid = blockIdx.x;
    const int swz = (bid & 7) * (1024 / 8) + (bid >> 3);
    const size_t row0 = (size_t)(swz >> 4) * BM;  // 64 M-tiles
    const size_t col0 = (size_t)(swz & 15) * BN;  // 16 N-tiles
    const uint8_t* Ab = Aq + row0 * K_DIM;
    const uint8_t* Bb = Bq + col0 * K_DIM;

    i32x4 acc[8][4];
#pragma unroll
    for (int i = 0; i < 8; ++i)
#pragma unroll
        for (int j = 0; j < 4; ++j) acc[i][j] = (i32x4){0, 0, 0, 0};

#define STAGE_A(DST, KT, MH)                                                     \
    do {                                                                         \
        _Pragma("unroll") for (int it_ = 0; it_ < 2; ++it_) {                    \
            const int m_ = (MH) * 64 + w * 8 + aa + it_ * 128;                   \
            async16(Ab + (size_t)m_ * K_DIM + (KT) * BK + ((pp ^ aa) << 4),      \
                    (DST) + ((MH) * 64 + w * 8 + it_ * 128) * BK);               \
        }                                                                        \
    } while (0)

#define STAGE_B(DST, KT, NH)                                                     \
    do {                                                                         \
        _Pragma("unroll") for (int it_ = 0; it_ < 2; ++it_) {                    \
            const int rwh_ = it_ * 64 + w * 8 + aa;                              \
            const int n_ = (NH) * 32 + (rwh_ & 31) + ((rwh_ >> 5) << 6);         \
            const int rw0_ = it_ * 64 + w * 8;                                   \
            const int nb_ = (NH) * 32 + (rw0_ & 31) + ((rw0_ >> 5) << 6);        \
            async16(Bb + (size_t)n_ * K_DIM + (KT) * BK + ((pp ^ aa) << 4),      \
                    (DST) + nb_ * BK);                                           \
        }                                                                        \
    } while (0)

#define READ_A(BUF, MH)                                                          \
    do {                                                                         \
        _Pragma("unroll") for (int mf_ = 0; mf_ < 4; ++mf_)                      \
        _Pragma("unroll") for (int kk_ = 0; kk_ < 2; ++kk_) {                    \
            const int r_ = wr * 128 + (MH) * 64 + mf_ * 16 + lr;                 \
            const int u_ = kk_ * 4 + lg;                                         \
            af[mf_][kk_] = *reinterpret_cast<const i32x4*>(                      \
                (BUF) + r_ * BK + ((u_ ^ (r_ & 7)) << 4));                       \
        }                                                                        \
    } while (0)

#define READ_B(BUF, NH, DSTF)                                                    \
    do {                                                                         \
        _Pragma("unroll") for (int nf_ = 0; nf_ < 2; ++nf_)                      \
        _Pragma("unroll") for (int kk_ = 0; kk_ < 2; ++kk_) {                    \
            const int r_ = wc * 64 + (NH) * 32 + nf_ * 16 + lr;                  \
            const int u_ = kk_ * 4 + lg;                                         \
            DSTF[nf_][kk_] = *reinterpret_cast<const i32x4*>(                    \
                (BUF) + r_ * BK + ((u_ ^ (r_ & 7)) << 4));                       \
        }                                                                        \
    } while (0)

#define MFMA_QUAD(MH, NH, BF)                                                    \
    do {                                                                         \
        __builtin_amdgcn_s_setprio(1);                                           \
        _Pragma("unroll") for (int mf_ = 0; mf_ < 4; ++mf_)                      \
        _Pragma("unroll") for (int nf_ = 0; nf_ < 2; ++nf_)                      \
        _Pragma("unroll") for (int kk_ = 0; kk_ < 2; ++kk_)                      \
            acc[(MH) * 4 + mf_][(NH) * 2 + nf_] =                                \
                __builtin_amdgcn_mfma_i32_16x16x64_i8(                           \
                    af[mf_][kk_], BF[nf_][kk_],                                  \
                    acc[(MH) * 4 + mf_][(NH) * 2 + nf_], 0, 0, 0);               \
        __builtin_amdgcn_s_setprio(0);                                           \
    } while (0)

#define BAR __builtin_amdgcn_s_barrier()
#define VMCNT6 asm volatile("s_waitcnt vmcnt(6)" ::: "memory")

    // ---- prologue: tile0 full -> buf0 (8 loads), tile1 A0,B0,B1 -> buf1 (6) ----
    STAGE_A(ldsA0, 0, 0);
    STAGE_A(ldsA0, 0, 1);
    STAGE_B(ldsB0, 0, 0);
    STAGE_B(ldsB0, 0, 1);
    STAGE_A(ldsA1, 1, 0);
    STAGE_B(ldsB1, 1, 0);
    STAGE_B(ldsB1, 1, 1);
    VMCNT6;  // tile0's 8 loads landed; tile1's 6 may be in flight
    BAR;

    i32x4 af[4][2], bfA[2][2], bfB[2][2];

#pragma unroll 1
    for (int it2 = 0; it2 < NT / 2; ++it2) {
        const int t = 2 * it2;
        const int kt2 = (t + 2 < NT) ? t + 2 : NT - 1;  // clamped tail stages
        const int kt3 = (t + 3 < NT) ? t + 3 : NT - 1;  // (write-safe, never read)

        // ======== tile t (buf0) ========
        READ_A(ldsA0, 0);
        READ_B(ldsB0, 0, bfA);
        STAGE_A(ldsA1, t + 1, 1);  // P1: A1(t+1)
        BAR;
        MFMA_QUAD(0, 0, bfA);
        BAR;

        READ_B(ldsB0, 1, bfB);
        STAGE_A(ldsA0, kt2, 0);    // P2: A0(t+2)
        BAR;
        MFMA_QUAD(0, 1, bfB);
        BAR;

        READ_A(ldsA0, 1);
        STAGE_B(ldsB0, kt2, 0);    // P3: B0(t+2)
        BAR;
        MFMA_QUAD(1, 1, bfB);
        BAR;

        STAGE_B(ldsB0, kt2, 1);    // P4: B1(t+2)
        BAR;
        MFMA_QUAD(1, 0, bfA);
        VMCNT6;                    // tile t+1 fully landed
        BAR;

        // ======== tile t+1 (buf1) ========
        READ_A(ldsA1, 0);
        READ_B(ldsB1, 0, bfA);
        STAGE_A(ldsA0, kt2, 1);    // P5: A1(t+2)
        BAR;
        MFMA_QUAD(0, 0, bfA);
        BAR;

        READ_B(ldsB1, 1, bfB);
        STAGE_A(ldsA1, kt3, 0);    // P6: A0(t+3)
        BAR;
        MFMA_QUAD(0, 1, bfB);
        BAR;

        READ_A(ldsA1, 1);
        STAGE_B(ldsB1, kt3, 0);    // P7: B0(t+3)
        BAR;
        MFMA_QUAD(1, 1, bfB);
        BAR;

        STAGE_B(ldsB1, kt3, 1);    // P8: B1(t+3)
        BAR;
        MFMA_QUAD(1, 0, bfA);
        VMCNT6;                    // tile t+2 fully landed
        BAR;
    }

    // ---- epilogue: C/D layout col = lane&15, row = (lane>>4)*4 + reg ----
    const float* asp = ascale + row0 + wr * 128;
    const float* wsp = wscale + col0 + wc * 64;
    float wsv[4];
#pragma unroll
    for (int nf = 0; nf < 4; ++nf) wsv[nf] = wsp[nf * 16 + lr];
    float* outBase = out + (row0 + wr * 128) * (size_t)N_DIM + col0 + wc * 64;
#pragma unroll
    for (int mf = 0; mf < 8; ++mf) {
#pragma unroll
        for (int j = 0; j < 4; ++j) {
            const int r = mf * 16 + lg * 4 + j;
            const float av = asp[r];
            float* orow = outBase + (size_t)r * N_DIM;
#pragma unroll
            for (int nf = 0; nf < 4; ++nf) {
                orow[nf * 16 + lr] = (float)acc[mf][nf][j] * av * wsv[nf];
            }
        }
    }
#undef STAGE_A
#undef STAGE_B
#undef READ_A
#undef READ_B
#undef MFMA_QUAD
#undef BAR
#undef VMCNT6
}

extern "C" void kernel_launch(void* const* d_in, const int* in_sizes, int n_in,
                              void* d_out, int out_size, void* d_ws, size_t ws_size,
                              hipStream_t stream) {
    const float* x = (const float*)d_in[0];
    const int* w32 = (const int*)d_in[1];
    const float* wscale = (const float*)d_in[2];
    float* out = (float*)d_out;

    uint8_t* ws = (uint8_t*)d_ws;
    uint32_t* xq = (uint32_t*)ws;                                  // 64 MiB
    float* xscale = (float*)(ws + (size_t)M_DIM * K_DIM);          // 64 KiB
    uint8_t* wq = ws + (size_t)M_DIM * K_DIM + (size_t)M_DIM * 4;  // 16 MiB

    pack_w_kernel<<<dim3((N_DIM * K_DIM / 4 + 255) / 256), 256, 0, stream>>>(
        w32, (uint32_t*)wq, N_DIM * K_DIM / 4);
    quant_kernel<<<dim3(M_DIM), 256, 0, stream>>>(x, xq, xscale);
    gemm_kernel<<<dim3((M_DIM / BM) * (N_DIM / BN)), 512, 0, stream>>>(
        (const uint8_t*)xq, xscale, wq, wscale, out);
}

// Round 3
// 343.975 us; speedup vs baseline: 1.0734x; 1.0074x over previous
//
#include <hip/hip_runtime.h>
#include <stdint.h>

#define M_DIM 16384
#define N_DIM 4096
#define K_DIM 4096

#define BM 256
#define BN 256
#define BK 128
#define NT (K_DIM / BK)  // 32 K-tiles

typedef int i32x4 __attribute__((ext_vector_type(4)));

// ---- async global->LDS 16B (dest = wave-uniform base, HW adds lane*16) ----
__device__ __forceinline__ void async16(const uint8_t* g, uint8_t* l) {
    __builtin_amdgcn_global_load_lds(
        (const __attribute__((address_space(1))) void*)g,
        (__attribute__((address_space(3))) void*)l,
        16, 0, 0);
}

// ---------------- weight pack: int32 -> int8 ----------------
__global__ __launch_bounds__(256) void pack_w_kernel(const int* __restrict__ w32,
                                                     uint32_t* __restrict__ w8,
                                                     int n4) {
    int i = blockIdx.x * 256 + threadIdx.x;
    if (i < n4) {
        const int4 v = reinterpret_cast<const int4*>(w32)[i];
        uint32_t p = (uint32_t)(v.x & 255) | ((uint32_t)(v.y & 255) << 8) |
                     ((uint32_t)(v.z & 255) << 16) | ((uint32_t)(v.w & 255) << 24);
        w8[i] = p;
    }
}

// ---------------- per-row dynamic activation quant ----------------
__global__ __launch_bounds__(256) void quant_kernel(const float* __restrict__ x,
                                                    uint32_t* __restrict__ xq,
                                                    float* __restrict__ xscale) {
    const int m = blockIdx.x;
    const int t = threadIdx.x;
    const float4* row = reinterpret_cast<const float4*>(x + (size_t)m * K_DIM);
    float4 v[4];
    float amax = 0.0f;
#pragma unroll
    for (int i = 0; i < 4; ++i) {
        v[i] = row[t + i * 256];
        amax = fmaxf(amax, fmaxf(fmaxf(fabsf(v[i].x), fabsf(v[i].y)),
                                 fmaxf(fabsf(v[i].z), fabsf(v[i].w))));
    }
#pragma unroll
    for (int off = 32; off > 0; off >>= 1) amax = fmaxf(amax, __shfl_xor(amax, off));
    __shared__ float smax[4];
    if ((t & 63) == 0) smax[t >> 6] = amax;
    __syncthreads();
    amax = fmaxf(fmaxf(smax[0], smax[1]), fmaxf(smax[2], smax[3]));
    const float scale = amax / 127.0f;
    const float s = fmaxf(scale, 1e-8f);
    if (t == 0) xscale[m] = scale;
    uint32_t* orow = xq + (size_t)m * (K_DIM / 4);
#pragma unroll
    for (int i = 0; i < 4; ++i) {
        int q0 = __float2int_rn(v[i].x / s);
        int q1 = __float2int_rn(v[i].y / s);
        int q2 = __float2int_rn(v[i].z / s);
        int q3 = __float2int_rn(v[i].w / s);
        q0 = max(-127, min(127, q0));
        q1 = max(-127, min(127, q1));
        q2 = max(-127, min(127, q2));
        q3 = max(-127, min(127, q3));
        uint32_t p = (uint32_t)(q0 & 255) | ((uint32_t)(q1 & 255) << 8) |
                     ((uint32_t)(q2 & 255) << 16) | ((uint32_t)(q3 & 255) << 24);
        orow[t + i * 256] = p;
    }
}

// ---------------- int8 GEMM, 256x256 8-phase schedule ----------------
// 512 threads = 8 waves (2M x 4N), per-wave output 128x64.
// K-tile BK=128 (128B rows). LDS: 2 x (A 32KB + B 32KB) = 128KB.
// Per-phase recipe (verified bf16 template): reads + stage issue, BAR,
// asm lgkmcnt(0) [memory fence: pins reads BEFORE the MFMA cluster],
// sched_barrier(0) [rule #18: stops MFMA hoisting above the fence],
// setprio(1), 16x MFMA, setprio(0), BAR. vmcnt(6) only at P4/P8.
__global__ __launch_bounds__(512, 2) void gemm_kernel(
    const uint8_t* __restrict__ Aq, const float* __restrict__ ascale,
    const uint8_t* __restrict__ Bq, const float* __restrict__ wscale,
    float* __restrict__ out) {
    __shared__ uint8_t lds[2 * BM * BK + 2 * BN * BK];
    uint8_t* ldsA0 = lds;
    uint8_t* ldsA1 = lds + BM * BK;
    uint8_t* ldsB0 = lds + 2 * BM * BK;
    uint8_t* ldsB1 = lds + 2 * BM * BK + BN * BK;

    const int tid = threadIdx.x;
    const int lane = tid & 63;
    const int w = tid >> 6;
    const int wr = w >> 2;    // 0..1 -> M offset wr*128
    const int wc = w & 3;     // 0..3 -> N offset wc*64
    const int lr = lane & 15; // row within 16x16 fragment
    const int lg = lane >> 4; // k-group 0..3 (16B each)
    const int aa = lane >> 3; // staging: row-within-8
    const int pp = lane & 7;  // staging: unit-within-row

    // XCD-aware bijective swizzle (1024 blocks, 1024%8==0)
    const int bid = blockIdx.x;
    const int swz = (bid & 7) * (1024 / 8) + (bid >> 3);
    const size_t row0 = (size_t)(swz >> 4) * BM;  // 64 M-tiles
    const size_t col0 = (size_t)(swz & 15) * BN;  // 16 N-tiles
    const uint8_t* Ab = Aq + row0 * K_DIM;
    const uint8_t* Bb = Bq + col0 * K_DIM;

    i32x4 acc[8][4];
#pragma unroll
    for (int i = 0; i < 8; ++i)
#pragma unroll
        for (int j = 0; j < 4; ++j) acc[i][j] = (i32x4){0, 0, 0, 0};

#define STAGE_A(DST, KT, MH)                                                     \
    do {                                                                         \
        _Pragma("unroll") for (int it_ = 0; it_ < 2; ++it_) {                    \
            const int m_ = (MH) * 64 + w * 8 + aa + it_ * 128;                   \
            async16(Ab + (size_t)m_ * K_DIM + (KT) * BK + ((pp ^ aa) << 4),      \
                    (DST) + ((MH) * 64 + w * 8 + it_ * 128) * BK);               \
        }                                                                        \
    } while (0)

#define STAGE_B(DST, KT, NH)                                                     \
    do {                                                                         \
        _Pragma("unroll") for (int it_ = 0; it_ < 2; ++it_) {                    \
            const int rwh_ = it_ * 64 + w * 8 + aa;                              \
            const int n_ = (NH) * 32 + (rwh_ & 31) + ((rwh_ >> 5) << 6);         \
            const int rw0_ = it_ * 64 + w * 8;                                   \
            const int nb_ = (NH) * 32 + (rw0_ & 31) + ((rw0_ >> 5) << 6);        \
            async16(Bb + (size_t)n_ * K_DIM + (KT) * BK + ((pp ^ aa) << 4),      \
                    (DST) + nb_ * BK);                                           \
        }                                                                        \
    } while (0)

#define READ_A(BUF, MH)                                                          \
    do {                                                                         \
        _Pragma("unroll") for (int mf_ = 0; mf_ < 4; ++mf_)                      \
        _Pragma("unroll") for (int kk_ = 0; kk_ < 2; ++kk_) {                    \
            const int r_ = wr * 128 + (MH) * 64 + mf_ * 16 + lr;                 \
            const int u_ = kk_ * 4 + lg;                                         \
            af[mf_][kk_] = *reinterpret_cast<const i32x4*>(                      \
                (BUF) + r_ * BK + ((u_ ^ (r_ & 7)) << 4));                       \
        }                                                                        \
    } while (0)

#define READ_B(BUF, NH, DSTF)                                                    \
    do {                                                                         \
        _Pragma("unroll") for (int nf_ = 0; nf_ < 2; ++nf_)                      \
        _Pragma("unroll") for (int kk_ = 0; kk_ < 2; ++kk_) {                    \
            const int r_ = wc * 64 + (NH) * 32 + nf_ * 16 + lr;                  \
            const int u_ = kk_ * 4 + lg;                                         \
            DSTF[nf_][kk_] = *reinterpret_cast<const i32x4*>(                    \
                (BUF) + r_ * BK + ((u_ ^ (r_ & 7)) << 4));                       \
        }                                                                        \
    } while (0)

#define MFMA_QUAD(MH, NH, BF)                                                    \
    do {                                                                         \
        __builtin_amdgcn_s_setprio(1);                                           \
        _Pragma("unroll") for (int mf_ = 0; mf_ < 4; ++mf_)                      \
        _Pragma("unroll") for (int nf_ = 0; nf_ < 2; ++nf_)                      \
        _Pragma("unroll") for (int kk_ = 0; kk_ < 2; ++kk_)                      \
            acc[(MH) * 4 + mf_][(NH) * 2 + nf_] =                                \
                __builtin_amdgcn_mfma_i32_16x16x64_i8(                           \
                    af[mf_][kk_], BF[nf_][kk_],                                  \
                    acc[(MH) * 4 + mf_][(NH) * 2 + nf_], 0, 0, 0);               \
        __builtin_amdgcn_s_setprio(0);                                           \
    } while (0)

#define BAR __builtin_amdgcn_s_barrier()
#define VMCNT6 asm volatile("s_waitcnt vmcnt(6)" ::: "memory")
// post-barrier fence: all ds_reads complete + compiler may not sink reads past
// it or hoist MFMAs above it (memory clobber + sched_barrier, rule #18)
#define LGKM0                                         \
    do {                                              \
        asm volatile("s_waitcnt lgkmcnt(0)" ::: "memory"); \
        __builtin_amdgcn_sched_barrier(0);            \
    } while (0)
// pre-barrier partial wait for 12-read phases: drain to 8 outstanding so the
// post-barrier lgkmcnt(0) is short
#define LGKM8 asm volatile("s_waitcnt lgkmcnt(8)" ::: "memory")

    // ---- prologue: tile0 full -> buf0 (8 loads), tile1 A0,B0,B1 -> buf1 (6) ----
    STAGE_A(ldsA0, 0, 0);
    STAGE_A(ldsA0, 0, 1);
    STAGE_B(ldsB0, 0, 0);
    STAGE_B(ldsB0, 0, 1);
    STAGE_A(ldsA1, 1, 0);
    STAGE_B(ldsB1, 1, 0);
    STAGE_B(ldsB1, 1, 1);
    VMCNT6;  // tile0's 8 loads landed; tile1's 6 may be in flight
    BAR;

    i32x4 af[4][2], bfA[2][2], bfB[2][2];

#pragma unroll 1
    for (int it2 = 0; it2 < NT / 2; ++it2) {
        const int t = 2 * it2;
        const int kt2 = (t + 2 < NT) ? t + 2 : NT - 1;  // clamped tail stages
        const int kt3 = (t + 3 < NT) ? t + 3 : NT - 1;  // (write-safe, never read)

        // ======== tile t (buf0) ========
        READ_A(ldsA0, 0);
        READ_B(ldsB0, 0, bfA);
        STAGE_A(ldsA1, t + 1, 1);  // P1: A1(t+1)
        LGKM8;
        BAR;
        LGKM0;
        MFMA_QUAD(0, 0, bfA);
        BAR;

        READ_B(ldsB0, 1, bfB);
        STAGE_A(ldsA0, kt2, 0);    // P2: A0(t+2)
        BAR;
        LGKM0;
        MFMA_QUAD(0, 1, bfB);
        BAR;

        READ_A(ldsA0, 1);
        STAGE_B(ldsB0, kt2, 0);    // P3: B0(t+2)
        BAR;
        LGKM0;
        MFMA_QUAD(1, 1, bfB);
        BAR;

        STAGE_B(ldsB0, kt2, 1);    // P4: B1(t+2)
        BAR;
        LGKM0;
        MFMA_QUAD(1, 0, bfA);
        VMCNT6;                    // tile t+1 fully landed
        BAR;

        // ======== tile t+1 (buf1) ========
        READ_A(ldsA1, 0);
        READ_B(ldsB1, 0, bfA);
        STAGE_A(ldsA0, kt2, 1);    // P5: A1(t+2)
        LGKM8;
        BAR;
        LGKM0;
        MFMA_QUAD(0, 0, bfA);
        BAR;

        READ_B(ldsB1, 1, bfB);
        STAGE_A(ldsA1, kt3, 0);    // P6: A0(t+3)
        BAR;
        LGKM0;
        MFMA_QUAD(0, 1, bfB);
        BAR;

        READ_A(ldsA1, 1);
        STAGE_B(ldsB1, kt3, 0);    // P7: B0(t+3)
        BAR;
        LGKM0;
        MFMA_QUAD(1, 1, bfB);
        BAR;

        STAGE_B(ldsB1, kt3, 1);    // P8: B1(t+3)
        BAR;
        LGKM0;
        MFMA_QUAD(1, 0, bfA);
        VMCNT6;                    // tile t+2 fully landed
        BAR;
    }

    // ---- epilogue: C/D layout col = lane&15, row = (lane>>4)*4 + reg ----
    const float* asp = ascale + row0 + wr * 128;
    const float* wsp = wscale + col0 + wc * 64;
    float wsv[4];
#pragma unroll
    for (int nf = 0; nf < 4; ++nf) wsv[nf] = wsp[nf * 16 + lr];
    float* outBase = out + (row0 + wr * 128) * (size_t)N_DIM + col0 + wc * 64;
#pragma unroll
    for (int mf = 0; mf < 8; ++mf) {
#pragma unroll
        for (int j = 0; j < 4; ++j) {
            const int r = mf * 16 + lg * 4 + j;
            const float av = asp[r];
            float* orow = outBase + (size_t)r * N_DIM;
#pragma unroll
            for (int nf = 0; nf < 4; ++nf) {
                orow[nf * 16 + lr] = (float)acc[mf][nf][j] * av * wsv[nf];
            }
        }
    }
#undef STAGE_A
#undef STAGE_B
#undef READ_A
#undef READ_B
#undef MFMA_QUAD
#undef BAR
#undef VMCNT6
#undef LGKM0
#undef LGKM8
}

extern "C" void kernel_launch(void* const* d_in, const int* in_sizes, int n_in,
                              void* d_out, int out_size, void* d_ws, size_t ws_size,
                              hipStream_t stream) {
    const float* x = (const float*)d_in[0];
    const int* w32 = (const int*)d_in[1];
    const float* wscale = (const float*)d_in[2];
    float* out = (float*)d_out;

    uint8_t* ws = (uint8_t*)d_ws;
    uint32_t* xq = (uint32_t*)ws;                                  // 64 MiB
    float* xscale = (float*)(ws + (size_t)M_DIM * K_DIM);          // 64 KiB
    uint8_t* wq = ws + (size_t)M_DIM * K_DIM + (size_t)M_DIM * 4;  // 16 MiB

    pack_w_kernel<<<dim3((N_DIM * K_DIM / 4 + 255) / 256), 256, 0, stream>>>(
        w32, (uint32_t*)wq, N_DIM * K_DIM / 4);
    quant_kernel<<<dim3(M_DIM), 256, 0, stream>>>(x, xq, xscale);
    gemm_kernel<<<dim3((M_DIM / BM) * (N_DIM / BN)), 512, 0, stream>>>(
        (const uint8_t*)xq, xscale, wq, wscale, out);
}